// Round 3
// baseline (151.389 us; speedup 1.0000x reference)
//
#include <hip/hip_runtime.h>
#include <stdint.h>

// Problem constants: t_q=64, t_k=128, b=32, n=1024
//   query (64,32,1024) f32 ; keys (128,32,1024) f32 ; Wq,Wk (1024,1024) f32
//   out0 = context (64,32,1024) f32 ; out1 = scores_softmax (64,32,128) f32
//
// Pipeline v4:
//  1) convert: f32->bf16 (q,k,Wq,Wk) + vnorm
//  2) proj_gemm (BK=128, 32 MFMA per barrier-pair, 48 KB LDS, 3 blk/CU):
//       q-side: ej  = exp2((q*Wq^T + bias)*C2), rows (q*32+b), cols u
//       k-side: ek2 = exp2((k*Wk^T)*C2) stored TRANSPOSED [b][u][k]
//  3) score_all (1024 thr, 2 blk/CU -> 32 waves/CU): scores over full u
//     (lane owns a k-pair, zero shuffles) -> LDS reduce -> softmax -> out_sc
//     -> context GEMV.

typedef __attribute__((ext_vector_type(8))) short bf16x8;
typedef __attribute__((ext_vector_type(4))) float f32x4;

#define C2_SCALE 2.8853900817779268f   // 2*log2(e)

__device__ __forceinline__ unsigned short f2bf(float x) {
    union { float f; uint32_t u; } v; v.f = x;
    uint32_t u = v.u;
    u += 0x7fffu + ((u >> 16) & 1u);   // round-to-nearest-even
    return (unsigned short)(u >> 16);
}

__device__ __forceinline__ float wave_sum(float x) {
#pragma unroll
    for (int off = 32; off; off >>= 1) x += __shfl_xor(x, off);
    return x;
}
__device__ __forceinline__ float wave_max(float x) {
#pragma unroll
    for (int off = 32; off; off >>= 1) x = fmaxf(x, __shfl_xor(x, off));
    return x;
}

// async 16B global -> LDS (wave-uniform base + lane*16 semantics)
__device__ __forceinline__ void gl2lds16(const void* g, void* l) {
    __builtin_amdgcn_global_load_lds(
        (const __attribute__((address_space(1))) void*)g,
        (__attribute__((address_space(3))) void*)l, 16, 0, 0);
}

// ------- f32 -> bf16 conversion of all 4 tensors + fused vnorm (blk 8192) ---
__global__ __launch_bounds__(256) void convert_kernel(
    const float* __restrict__ q, const float* __restrict__ k,
    const float* __restrict__ wq, const float* __restrict__ wk,
    unsigned short* __restrict__ qb, unsigned short* __restrict__ kb,
    unsigned short* __restrict__ wqb, unsigned short* __restrict__ wkb,
    const float* __restrict__ la, const float* __restrict__ ns,
    float* __restrict__ v) {
    __shared__ float red[4], red2[4];
    if (blockIdx.x == 8192) {
        // vnorm: v = la/||la|| * ns; v[1024] = sum(v)
        int tid = threadIdx.x, w = tid >> 6;
        float s = 0.f;
        for (int i = tid; i < 1024; i += 256) { float x = la[i]; s += x * x; }
        s = wave_sum(s);
        if ((tid & 63) == 0) red[w] = s;
        __syncthreads();
        float scale = rsqrtf(red[0] + red[1] + red[2] + red[3]) * ns[0];
        float vp = 0.f;
        for (int i = tid; i < 1024; i += 256) { float vv = la[i] * scale; v[i] = vv; vp += vv; }
        vp = wave_sum(vp);
        if ((tid & 63) == 0) red2[w] = vp;
        __syncthreads();
        if (tid == 0) v[1024] = red2[0] + red2[1] + red2[2] + red2[3];
        return;
    }
    int idx = blockIdx.x * 256 + threadIdx.x;   // float4 index; 2097152 total
    int e = idx * 4;
    const float* src; unsigned short* dst; int off;
    if (e < 2097152)      { src = q;  dst = qb;  off = e; }
    else if (e < 6291456) { src = k;  dst = kb;  off = e - 2097152; }
    else if (e < 7340032) { src = wq; dst = wqb; off = e - 6291456; }
    else                  { src = wk; dst = wkb; off = e - 7340032; }
    float4 xv = *(const float4*)(src + off);
    ushort4 o;
    o.x = f2bf(xv.x); o.y = f2bf(xv.y); o.z = f2bf(xv.z); o.w = f2bf(xv.w);
    *(ushort4*)(dst + off) = o;
}

// ---------------- combined projection GEMM (bf16 -> f32), BK=128 ------------
// Row-group swizzle: XCD = linear_id % 8 = blockIdx.x (since 8 | 8*y).
//   rowt = blockIdx.x * 12 + (blockIdx.y >> 3)   (0..95)
//   col0 = (blockIdx.y & 7) * 128
// rowt 0..31  -> q-part: rows (q*32+b) consecutive, arow = rowt*64
//                epilogue: ej[row][col] = exp2((acc + bias[col])*C2)
// rowt 32..95 -> k-part: t = rowt-32: b0 = t&31, k0 = (t>>5)*64
//                row set = {(k0+s)*32 + b0 : s = 0..63}  (fixed b!)
//                epilogue: LDS transpose -> ek2[(b0*1024+u)*128 + k]
// 64-row x 128-col tile, BK=128: 8 K-iters x (12 gl2lds + 32 MFMA).
// LDS 16+32 KB; epilogue 33 KB aliases. 3 blocks/CU (144 KB LDS).
// XOR swizzle: LDS[row][c] = global[row][c ^ (row&15)], c = 8-elem chunk 0..15
// -> read-side lanes (ml 0..15) spread over 8 bank-groups, 2-way = free.
__global__ __launch_bounds__(256) void proj_gemm(
    const unsigned short* __restrict__ qb, const unsigned short* __restrict__ kb,
    const unsigned short* __restrict__ wqb, const unsigned short* __restrict__ wkb,
    const float* __restrict__ bias,
    float* __restrict__ ej, float* __restrict__ ek2) {
    __shared__ __align__(16) unsigned char smem[49152];
    unsigned short* As = (unsigned short*)smem;             // 16 KB [64][128]
    unsigned short* Bs = (unsigned short*)(smem + 16384);   // 32 KB [128][128]
    float* ep = (float*)smem;                               // 33 KB, k-epilogue only

    int col0 = (blockIdx.y & 7) * 128;
    int rowt = blockIdx.x * 12 + (blockIdx.y >> 3);   // 0..95
    int tid = threadIdx.x;
    int w = tid >> 6, lane = tid & 63;
    int wm = w >> 1, wn = w & 1;          // 2x2 waves
    int ml = lane & 15, quad = lane >> 4;

    bool is_k = rowt >= 32;
    const unsigned short* A; const unsigned short* Bm;
    int base, rstride, arow = 0, b0 = 0, k0g = 0;
    if (!is_k) {
        A = qb; Bm = wqb; arow = rowt * 64;
        base = arow * 1024; rstride = 1024;
    } else {
        int t = rowt - 32;
        b0 = t & 31; k0g = (t >> 5) * 64;
        A = kb; Bm = wkb;
        base = (k0g * 32 + b0) * 1024; rstride = 32 * 1024;
    }

    // staging: 16 lanes/row (256B = BK), 16 rows per gl2lds call
    int srow = tid >> 4;                       // 0..15
    int kxor = (tid & 15) ^ srow;              // row&15 == srow for all calls
    const unsigned short* ga = A + base + srow * rstride + kxor * 8;
    const unsigned short* gb = Bm + (col0 + srow) * 1024 + kxor * 8;
    unsigned short* la = &As[tid * 8];
    unsigned short* lb = &Bs[tid * 8];

    f32x4 acc[2][4];
#pragma unroll
    for (int i = 0; i < 2; i++)
#pragma unroll
        for (int j = 0; j < 4; j++) acc[i][j] = (f32x4)(0.f);

    for (int kk0 = 0; kk0 < 1024; kk0 += 128) {
        __syncthreads();
#pragma unroll
        for (int t = 0; t < 4; t++)
            gl2lds16(ga + t * 16 * rstride + kk0, la + t * 2048);
#pragma unroll
        for (int t = 0; t < 8; t++)
            gl2lds16(gb + t * 16 * 1024 + kk0, lb + t * 2048);
        __syncthreads();
#pragma unroll
        for (int ks = 0; ks < 4; ks++) {
            int kcol = ((ks * 4 + quad) ^ ml) * 8;
            bf16x8 a[2], b[4];
#pragma unroll
            for (int i = 0; i < 2; i++)
                a[i] = *(const bf16x8*)&As[(wm * 32 + i * 16 + ml) * 128 + kcol];
#pragma unroll
            for (int j = 0; j < 4; j++)
                b[j] = *(const bf16x8*)&Bs[(wn * 64 + j * 16 + ml) * 128 + kcol];
#pragma unroll
            for (int i = 0; i < 2; i++)
#pragma unroll
                for (int j = 0; j < 4; j++)
                    acc[i][j] = __builtin_amdgcn_mfma_f32_16x16x32_bf16(a[i], b[j], acc[i][j], 0, 0, 0);
        }
    }

    // C/D layout: col = lane&15, row = quad*4 + reg
    if (!is_k) {
        // q-part: ej = exp2((acc + bias)*C2), straight row-major store
#pragma unroll
        for (int i = 0; i < 2; i++)
#pragma unroll
            for (int j = 0; j < 4; j++) {
                int colg = col0 + wn * 64 + j * 16 + ml;
                float bj = bias[colg];
#pragma unroll
                for (int r = 0; r < 4; r++) {
                    int row = arow + wm * 32 + i * 16 + quad * 4 + r;
                    ej[row * 1024 + colg] =
                        __builtin_amdgcn_exp2f((acc[i][j][r] + bj) * C2_SCALE);
                }
            }
    } else {
        // k-part: exp2, restage through LDS, store transposed (k innermost)
        __syncthreads();   // all waves done reading As/Bs before ep overwrite
#pragma unroll
        for (int i = 0; i < 2; i++)
#pragma unroll
            for (int j = 0; j < 4; j++) {
                int col = wn * 64 + j * 16 + ml;
#pragma unroll
                for (int r = 0; r < 4; r++) {
                    int krel = wm * 32 + i * 16 + quad * 4 + r;
                    ep[krel * 129 + col] =
                        __builtin_amdgcn_exp2f(acc[i][j][r] * C2_SCALE);
                }
            }
        __syncthreads();
        int ur = tid >> 4;            // 0..15
        int kq = (tid & 15) * 4;      // k quad base 0..60
#pragma unroll
        for (int it = 0; it < 8; it++) {
            int u = it * 16 + ur;     // 0..127
            float4 o;
            o.x = ep[(kq + 0) * 129 + u];
            o.y = ep[(kq + 1) * 129 + u];
            o.z = ep[(kq + 2) * 129 + u];
            o.w = ep[(kq + 3) * 129 + u];
            *(float4*)(ek2 + (b0 * 1024 + col0 + u) * 128 + k0g + kq) = o;
        }
    }
}

// ---------------- merged score + softmax + context --------------------------
// Grid (32 b, 16 qt) = 512 blocks, 1024 thr -> 2 blocks/CU = 32 waves/CU.
// Phase 1 (scores): thread (kp = tid&63 k-pair, uc = tid>>6 in 0..15 owning a
//   64-u chunk). ej[4][1024] + v[1024] broadcast from LDS; ek2 streamed
//   coalesced. Pairing identity over adjacent u:
//   v0/(1+A)+v1/(1+B) = (v0*B1+v1*A1)*rcp(A1*B1). Zero cross-lane shuffles.
// Phase 2: LDS-combine 16 uc partials -> sc = vsum - 2*s; softmax (once);
//   write out_sc. Phase 3: context GEMV, thread owns 1 n x 4 q; keys slab
//   L2-resident (block id = b + 32*qt -> XCD = b%8 for all qt of one b).
__global__ __launch_bounds__(1024, 8) void score_all(
    const float* __restrict__ ej, const float* __restrict__ ek2,
    const float* __restrict__ v, const float* __restrict__ keys,
    float* __restrict__ out_ctx, float* __restrict__ out_sc) {
    __shared__ float ejs[4][1024];       // 16 KB
    __shared__ float vs[1024];           // 4 KB
    __shared__ float red[16][64][9];     // 36 KB (pad 9 -> conflict-free)
    __shared__ float sc[4][128];         // 2 KB
    const float L2E = 1.4426950408889634f;
    int b = blockIdx.x, qt = blockIdx.y;
    int q0 = qt * 4;
    int tid = threadIdx.x;
    float vsum = v[1024];

    {   // stage ej (4 rows x 1024) + v (1024) into LDS, fully coalesced
        int j = tid >> 8, uu = (tid & 255) * 4;
        *(float4*)&ejs[j][uu] =
            *(const float4*)(ej + ((q0 + j) * 32 + b) * 1024 + uu);
        if (tid < 256) *(float4*)&vs[tid * 4] = *(const float4*)(v + tid * 4);
    }
    __syncthreads();

    int kp = tid & 63, uc = tid >> 6;          // uc 0..15, 64 u each
    const float* ekp = ek2 + (b * 1024 + uc * 64) * 128 + kp * 2;

    float a[4][2];
#pragma unroll
    for (int j = 0; j < 4; j++) { a[j][0] = 0.f; a[j][1] = 0.f; }

#pragma unroll 2
    for (int ui = 0; ui < 64; ui += 4) {
        float2 e0 = *(const float2*)(ekp);          // ek2[u]  [2k]
        float2 e1 = *(const float2*)(ekp + 128);    // ek2[u+1][2k]
        float2 e2 = *(const float2*)(ekp + 256);
        float2 e3 = *(const float2*)(ekp + 384);
        ekp += 512;
        float4 vv = *(const float4*)&vs[uc * 64 + ui];
#pragma unroll
        for (int j = 0; j < 4; j++) {
            float4 ee = *(const float4*)&ejs[j][uc * 64 + ui];
            float A1 = fmaf(ee.x, e0.x, 1.f);
            float B1 = fmaf(ee.y, e1.x, 1.f);
            a[j][0] = fmaf(fmaf(vv.x, B1, vv.y * A1),
                           __builtin_amdgcn_rcpf(A1 * B1), a[j][0]);
            float A2 = fmaf(ee.x, e0.y, 1.f);
            float B2 = fmaf(ee.y, e1.y, 1.f);
            a[j][1] = fmaf(fmaf(vv.x, B2, vv.y * A2),
                           __builtin_amdgcn_rcpf(A2 * B2), a[j][1]);
            float C1 = fmaf(ee.z, e2.x, 1.f);
            float D1 = fmaf(ee.w, e3.x, 1.f);
            a[j][0] = fmaf(fmaf(vv.z, D1, vv.w * C1),
                           __builtin_amdgcn_rcpf(C1 * D1), a[j][0]);
            float C2 = fmaf(ee.z, e2.y, 1.f);
            float D2 = fmaf(ee.w, e3.y, 1.f);
            a[j][1] = fmaf(fmaf(vv.z, D2, vv.w * C2),
                           __builtin_amdgcn_rcpf(C2 * D2), a[j][1]);
        }
    }

    // combine the 16 uc partials per (q, k) through LDS
#pragma unroll
    for (int j = 0; j < 4; j++) {
        red[uc][kp][j * 2 + 0] = a[j][0];
        red[uc][kp][j * 2 + 1] = a[j][1];
    }
    __syncthreads();
    if (tid < 512) {
        int j = tid >> 7, k = tid & 127;
        int kp2 = k >> 1, c = k & 1;
        float s = 0.f;
#pragma unroll
        for (int u = 0; u < 16; u++) s += red[u][kp2][j * 2 + c];
        sc[j][k] = vsum - 2.f * s;
    }
    __syncthreads();

    // softmax over k (128): waves 0..3 handle q-row j=w; lanes cover k, k+64
    int w = tid >> 6, lane = tid & 63;
    if (w < 4) {
        int j = w;
        float s1 = sc[j][lane], s2 = sc[j][lane + 64];
        float m = wave_max(fmaxf(s1, s2));
        float e1 = __builtin_amdgcn_exp2f((s1 - m) * L2E);
        float e2 = __builtin_amdgcn_exp2f((s2 - m) * L2E);
        float ssum = wave_sum(e1 + e2);
        float inv = __builtin_amdgcn_rcpf(ssum);
        float p1 = e1 * inv, p2 = e2 * inv;
        sc[j][lane] = p1; sc[j][lane + 64] = p2;
        float* o = out_sc + ((q0 + j) * 32 + b) * 128;
        o[lane] = p1; o[lane + 64] = p2;
    }
    __syncthreads();

    // context[j][n] = sum_k p[j][k] * keys[k][b][n]; thread owns 1 n, 4 rows
    {
        int n0 = tid;
        const float* kbase = keys + b * 1024 + n0;
        float c0 = 0.f, c1 = 0.f, c2 = 0.f, c3 = 0.f;
#pragma unroll 4
        for (int k = 0; k < 128; k++) {
            float kv = kbase[k * 32768];
            c0 = fmaf(sc[0][k], kv, c0);
            c1 = fmaf(sc[1][k], kv, c1);
            c2 = fmaf(sc[2][k], kv, c2);
            c3 = fmaf(sc[3][k], kv, c3);
        }
        out_ctx[((q0 + 0) * 32 + b) * 1024 + n0] = c0;
        out_ctx[((q0 + 1) * 32 + b) * 1024 + n0] = c1;
        out_ctx[((q0 + 2) * 32 + b) * 1024 + n0] = c2;
        out_ctx[((q0 + 3) * 32 + b) * 1024 + n0] = c3;
    }
}

extern "C" void kernel_launch(void* const* d_in, const int* in_sizes, int n_in,
                              void* d_out, int out_size, void* d_ws, size_t ws_size,
                              hipStream_t stream) {
    const float* query = (const float*)d_in[0];
    const float* keys  = (const float*)d_in[1];
    const float* Wq    = (const float*)d_in[2];
    const float* Wk    = (const float*)d_in[3];
    const float* la    = (const float*)d_in[4];
    const float* ns    = (const float*)d_in[5];
    const float* bias  = (const float*)d_in[6];

    float* out_ctx = (float*)d_out;             // 64*32*1024
    float* out_sc  = (float*)d_out + 2097152;   // 64*32*128

    char* ws = (char*)d_ws;                     // ~38 MB used
    float* v   = (float*)(ws);                  // 1025 floats
    float* ej  = (float*)(ws + 8192);           // 8 MB  [2048 rows][1024 u]
    float* ek2 = (float*)(ws + 8192 + 8388608); // 16 MB [b][u][k]
    unsigned short* qb  = (unsigned short*)(ws + 8192 + 8388608 + 16777216);
    unsigned short* kb  = qb + 2097152;
    unsigned short* wqb = kb + 4194304;
    unsigned short* wkb = wqb + 1048576;

    convert_kernel<<<8193, 256, 0, stream>>>(query, keys, Wq, Wk, qb, kb, wqb, wkb,
                                             la, ns, v);
    proj_gemm<<<dim3(8, 96), 256, 0, stream>>>(qb, kb, wqb, wkb, bias, ej, ek2);
    score_all<<<dim3(32, 16), 1024, 0, stream>>>(ej, ek2, v, keys, out_ctx, out_sc);
}

// Round 4
// 149.527 us; speedup vs baseline: 1.0125x; 1.0125x over previous
//
#include <hip/hip_runtime.h>
#include <stdint.h>

// Problem constants: t_q=64, t_k=128, b=32, n=1024
//   query (64,32,1024) f32 ; keys (128,32,1024) f32 ; Wq,Wk (1024,1024) f32
//   out0 = context (64,32,1024) f32 ; out1 = scores_softmax (64,32,128) f32
//
// Pipeline v5:
//  1) convert: f32->bf16 (q,k,Wq,Wk) + vnorm
//  2) proj_gemm (BK=128): q-side ej = exp2((q*Wq^T + bias)*C2);
//     k-side ek2 = exp2((k*Wk^T)*C2) stored TRANSPOSED [b][u][k]
//  3) score_all: 512 thr, <=128 VGPR, software-pipelined inner loop
//     (register ping-pong on global e-loads + LDS ejt broadcasts),
//     zero cross-lane ops -> LDS reduce -> softmax -> context GEMV.

typedef __attribute__((ext_vector_type(8))) short bf16x8;
typedef __attribute__((ext_vector_type(4))) float f32x4;

#define C2_SCALE 2.8853900817779268f   // 2*log2(e)

__device__ __forceinline__ unsigned short f2bf(float x) {
    union { float f; uint32_t u; } v; v.f = x;
    uint32_t u = v.u;
    u += 0x7fffu + ((u >> 16) & 1u);   // round-to-nearest-even
    return (unsigned short)(u >> 16);
}

__device__ __forceinline__ float wave_sum(float x) {
#pragma unroll
    for (int off = 32; off; off >>= 1) x += __shfl_xor(x, off);
    return x;
}
__device__ __forceinline__ float wave_max(float x) {
#pragma unroll
    for (int off = 32; off; off >>= 1) x = fmaxf(x, __shfl_xor(x, off));
    return x;
}

// async 16B global -> LDS (wave-uniform base + lane*16 semantics)
__device__ __forceinline__ void gl2lds16(const void* g, void* l) {
    __builtin_amdgcn_global_load_lds(
        (const __attribute__((address_space(1))) void*)g,
        (__attribute__((address_space(3))) void*)l, 16, 0, 0);
}

// ------- f32 -> bf16 conversion of all 4 tensors + fused vnorm (blk 8192) ---
__global__ __launch_bounds__(256) void convert_kernel(
    const float* __restrict__ q, const float* __restrict__ k,
    const float* __restrict__ wq, const float* __restrict__ wk,
    unsigned short* __restrict__ qb, unsigned short* __restrict__ kb,
    unsigned short* __restrict__ wqb, unsigned short* __restrict__ wkb,
    const float* __restrict__ la, const float* __restrict__ ns,
    float* __restrict__ v) {
    __shared__ float red[4], red2[4];
    if (blockIdx.x == 8192) {
        // vnorm: v = la/||la|| * ns; v[1024] = sum(v)
        int tid = threadIdx.x, w = tid >> 6;
        float s = 0.f;
        for (int i = tid; i < 1024; i += 256) { float x = la[i]; s += x * x; }
        s = wave_sum(s);
        if ((tid & 63) == 0) red[w] = s;
        __syncthreads();
        float scale = rsqrtf(red[0] + red[1] + red[2] + red[3]) * ns[0];
        float vp = 0.f;
        for (int i = tid; i < 1024; i += 256) { float vv = la[i] * scale; v[i] = vv; vp += vv; }
        vp = wave_sum(vp);
        if ((tid & 63) == 0) red2[w] = vp;
        __syncthreads();
        if (tid == 0) v[1024] = red2[0] + red2[1] + red2[2] + red2[3];
        return;
    }
    int idx = blockIdx.x * 256 + threadIdx.x;   // float4 index; 2097152 total
    int e = idx * 4;
    const float* src; unsigned short* dst; int off;
    if (e < 2097152)      { src = q;  dst = qb;  off = e; }
    else if (e < 6291456) { src = k;  dst = kb;  off = e - 2097152; }
    else if (e < 7340032) { src = wq; dst = wqb; off = e - 6291456; }
    else                  { src = wk; dst = wkb; off = e - 7340032; }
    float4 xv = *(const float4*)(src + off);
    ushort4 o;
    o.x = f2bf(xv.x); o.y = f2bf(xv.y); o.z = f2bf(xv.z); o.w = f2bf(xv.w);
    *(ushort4*)(dst + off) = o;
}

// ---------------- combined projection GEMM (bf16 -> f32), BK=128 ------------
// Row-group swizzle: XCD = linear_id % 8 = blockIdx.x (since 8 | 8*y).
//   rowt = blockIdx.x * 12 + (blockIdx.y >> 3)   (0..95)
//   col0 = (blockIdx.y & 7) * 128
// rowt 0..31  -> q-part: rows (q*32+b) consecutive, arow = rowt*64
//                epilogue: ej[row][col] = exp2((acc + bias[col])*C2)
// rowt 32..95 -> k-part: t = rowt-32: b0 = t&31, k0 = (t>>5)*64
//                row set = {(k0+s)*32 + b0 : s = 0..63}  (fixed b!)
//                epilogue: LDS transpose -> ek2[(b0*1024+u)*128 + k]
// 64-row x 128-col tile, BK=128: 8 K-iters x (12 gl2lds + 32 MFMA).
// LDS 16+32 KB; epilogue 33 KB aliases. 3 blocks/CU (144 KB LDS).
// XOR swizzle: LDS[row][c] = global[row][c ^ (row&15)], c = 8-elem chunk 0..15
__global__ __launch_bounds__(256) void proj_gemm(
    const unsigned short* __restrict__ qb, const unsigned short* __restrict__ kb,
    const unsigned short* __restrict__ wqb, const unsigned short* __restrict__ wkb,
    const float* __restrict__ bias,
    float* __restrict__ ej, float* __restrict__ ek2) {
    __shared__ __align__(16) unsigned char smem[49152];
    unsigned short* As = (unsigned short*)smem;             // 16 KB [64][128]
    unsigned short* Bs = (unsigned short*)(smem + 16384);   // 32 KB [128][128]
    float* ep = (float*)smem;                               // 33 KB, k-epilogue only

    int col0 = (blockIdx.y & 7) * 128;
    int rowt = blockIdx.x * 12 + (blockIdx.y >> 3);   // 0..95
    int tid = threadIdx.x;
    int w = tid >> 6, lane = tid & 63;
    int wm = w >> 1, wn = w & 1;          // 2x2 waves
    int ml = lane & 15, quad = lane >> 4;

    bool is_k = rowt >= 32;
    const unsigned short* A; const unsigned short* Bm;
    int base, rstride, arow = 0, b0 = 0, k0g = 0;
    if (!is_k) {
        A = qb; Bm = wqb; arow = rowt * 64;
        base = arow * 1024; rstride = 1024;
    } else {
        int t = rowt - 32;
        b0 = t & 31; k0g = (t >> 5) * 64;
        A = kb; Bm = wkb;
        base = (k0g * 32 + b0) * 1024; rstride = 32 * 1024;
    }

    // staging: 16 lanes/row (256B = BK), 16 rows per gl2lds call
    int srow = tid >> 4;                       // 0..15
    int kxor = (tid & 15) ^ srow;              // row&15 == srow for all calls
    const unsigned short* ga = A + base + srow * rstride + kxor * 8;
    const unsigned short* gb = Bm + (col0 + srow) * 1024 + kxor * 8;
    unsigned short* la = &As[tid * 8];
    unsigned short* lb = &Bs[tid * 8];

    f32x4 acc[2][4];
#pragma unroll
    for (int i = 0; i < 2; i++)
#pragma unroll
        for (int j = 0; j < 4; j++) acc[i][j] = (f32x4)(0.f);

    for (int kk0 = 0; kk0 < 1024; kk0 += 128) {
        __syncthreads();
#pragma unroll
        for (int t = 0; t < 4; t++)
            gl2lds16(ga + t * 16 * rstride + kk0, la + t * 2048);
#pragma unroll
        for (int t = 0; t < 8; t++)
            gl2lds16(gb + t * 16 * 1024 + kk0, lb + t * 2048);
        __syncthreads();
#pragma unroll
        for (int ks = 0; ks < 4; ks++) {
            int kcol = ((ks * 4 + quad) ^ ml) * 8;
            bf16x8 a[2], b[4];
#pragma unroll
            for (int i = 0; i < 2; i++)
                a[i] = *(const bf16x8*)&As[(wm * 32 + i * 16 + ml) * 128 + kcol];
#pragma unroll
            for (int j = 0; j < 4; j++)
                b[j] = *(const bf16x8*)&Bs[(wn * 64 + j * 16 + ml) * 128 + kcol];
#pragma unroll
            for (int i = 0; i < 2; i++)
#pragma unroll
                for (int j = 0; j < 4; j++)
                    acc[i][j] = __builtin_amdgcn_mfma_f32_16x16x32_bf16(a[i], b[j], acc[i][j], 0, 0, 0);
        }
    }

    // C/D layout: col = lane&15, row = quad*4 + reg
    if (!is_k) {
        // q-part: ej = exp2((acc + bias)*C2), straight row-major store
#pragma unroll
        for (int i = 0; i < 2; i++)
#pragma unroll
            for (int j = 0; j < 4; j++) {
                int colg = col0 + wn * 64 + j * 16 + ml;
                float bj = bias[colg];
#pragma unroll
                for (int r = 0; r < 4; r++) {
                    int row = arow + wm * 32 + i * 16 + quad * 4 + r;
                    ej[row * 1024 + colg] =
                        __builtin_amdgcn_exp2f((acc[i][j][r] + bj) * C2_SCALE);
                }
            }
    } else {
        // k-part: exp2, restage through LDS, store transposed (k innermost)
        __syncthreads();   // all waves done reading As/Bs before ep overwrite
#pragma unroll
        for (int i = 0; i < 2; i++)
#pragma unroll
            for (int j = 0; j < 4; j++) {
                int col = wn * 64 + j * 16 + ml;
#pragma unroll
                for (int r = 0; r < 4; r++) {
                    int krel = wm * 32 + i * 16 + quad * 4 + r;
                    ep[krel * 129 + col] =
                        __builtin_amdgcn_exp2f(acc[i][j][r] * C2_SCALE);
                }
            }
        __syncthreads();
        int ur = tid >> 4;            // 0..15
        int kq = (tid & 15) * 4;      // k quad base 0..60
#pragma unroll
        for (int it = 0; it < 8; it++) {
            int u = it * 16 + ur;     // 0..127
            float4 o;
            o.x = ep[(kq + 0) * 129 + u];
            o.y = ep[(kq + 1) * 129 + u];
            o.z = ep[(kq + 2) * 129 + u];
            o.w = ep[(kq + 3) * 129 + u];
            *(float4*)(ek2 + (b0 * 1024 + col0 + u) * 128 + k0g + kq) = o;
        }
    }
}

// ---------------- merged score + softmax + context --------------------------
// Grid (32 b, 16 qt) = 512 blocks, 512 thr, launch_bounds(512,4) -> <=128
// VGPR, 2 blocks/CU, 16 waves/CU.
// Phase 1: thread (kp = tid&63 k-pair, uc = tid>>6 in 0..7 owning 128 u).
//   2-stage register ping-pong pipeline: step s+1's 4 global float2 (ek2) +
//   4 LDS float4 (ejt, wave-uniform broadcast) + vv issued before computing
//   step s. ejt stored TRANSPOSED [u][4 q] so one b128 covers all q.
//   Pairing identity: v0/(1+A)+v1/(1+B) = (v0*B1+v1*A1)*rcp(A1*B1).
// Phase 2: packed float4 partial writes -> LDS reduce (8 chunks) -> sc.
// Phase 3: softmax once -> out_sc + sct[k][4q]; context GEMV (2 n x 4 q per
//   thread, float2 keys loads; keys slab L2-resident, XCD = b%8).
__global__ __launch_bounds__(512, 4) void score_all(
    const float* __restrict__ ej, const float* __restrict__ ek2,
    const float* __restrict__ v, const float* __restrict__ keys,
    float* __restrict__ out_ctx, float* __restrict__ out_sc) {
    __shared__ float ejt[1024 * 4];      // 16 KB  [u][j]
    __shared__ float vs[1024];           // 4 KB
    __shared__ float red[8][64][8];      // 16 KB packed float4 x2
    __shared__ float sc[4][128];         // 2 KB
    __shared__ float sct[128][4];        // 2 KB   [k][j] for GEMV
    const float L2E = 1.4426950408889634f;
    int b = blockIdx.x, qt = blockIdx.y;
    int q0 = qt * 4;
    int tid = threadIdx.x;
    float vsum = v[1024];

    {   // stage ej transposed: ejt[u][j] = ej[(q0+j)*32+b][u]
        int r = tid & 3, uq = tid >> 2;       // j = r, u-quad = uq (0..127)
#pragma unroll
        for (int p = 0; p < 2; p++) {
            int u0 = p * 512 + uq * 4;
            float4 x = *(const float4*)(ej + ((q0 + r) * 32 + b) * 1024 + u0);
            ejt[(u0 + 0) * 4 + r] = x.x;
            ejt[(u0 + 1) * 4 + r] = x.y;
            ejt[(u0 + 2) * 4 + r] = x.z;
            ejt[(u0 + 3) * 4 + r] = x.w;
        }
        if (tid < 256) *(float4*)&vs[tid * 4] = *(const float4*)(v + tid * 4);
    }
    __syncthreads();

    int kp = tid & 63, uc = tid >> 6;          // uc 0..7, 128 u each
    const float* ekg = ek2 + (b * 1024 + uc * 128) * 128 + kp * 2;
    const float* ejb = &ejt[(uc * 128) * 4];
    const float* vvb = &vs[uc * 128];

    float a[4][2];
#pragma unroll
    for (int j = 0; j < 4; j++) { a[j][0] = 0.f; a[j][1] = 0.f; }

    float2 e0A, e1A, e2A, e3A, e0B, e1B, e2B, e3B;
    float4 t0A, t1A, t2A, t3A, t0B, t1B, t2B, t3B, vvA, vvB;

#define LOADS(S, goff, s)                                        \
    e0##S = *(const float2*)(ekg + (goff) + 0);                  \
    e1##S = *(const float2*)(ekg + (goff) + 128);                \
    e2##S = *(const float2*)(ekg + (goff) + 256);                \
    e3##S = *(const float2*)(ekg + (goff) + 384);                \
    t0##S = *(const float4*)(ejb + ((s) * 4 + 0) * 4);           \
    t1##S = *(const float4*)(ejb + ((s) * 4 + 1) * 4);           \
    t2##S = *(const float4*)(ejb + ((s) * 4 + 2) * 4);           \
    t3##S = *(const float4*)(ejb + ((s) * 4 + 3) * 4);           \
    vv##S = *(const float4*)(vvb + (s) * 4);

#define COMP(S)                                                  \
    _Pragma("unroll")                                            \
    for (int j = 0; j < 4; j++) {                                \
        float A1 = fmaf(t0##S[j], e0##S.x, 1.f);                 \
        float B1 = fmaf(t1##S[j], e1##S.x, 1.f);                 \
        a[j][0] = fmaf(fmaf(vv##S.x, B1, vv##S.y * A1),          \
                       __builtin_amdgcn_rcpf(A1 * B1), a[j][0]); \
        float A2 = fmaf(t0##S[j], e0##S.y, 1.f);                 \
        float B2 = fmaf(t1##S[j], e1##S.y, 1.f);                 \
        a[j][1] = fmaf(fmaf(vv##S.x, B2, vv##S.y * A2),          \
                       __builtin_amdgcn_rcpf(A2 * B2), a[j][1]); \
        float C1 = fmaf(t2##S[j], e2##S.x, 1.f);                 \
        float D1 = fmaf(t3##S[j], e3##S.x, 1.f);                 \
        a[j][0] = fmaf(fmaf(vv##S.z, D1, vv##S.w * C1),          \
                       __builtin_amdgcn_rcpf(C1 * D1), a[j][0]); \
        float C2 = fmaf(t2##S[j], e2##S.y, 1.f);                 \
        float D2 = fmaf(t3##S[j], e3##S.y, 1.f);                 \
        a[j][1] = fmaf(fmaf(vv##S.z, D2, vv##S.w * C2),          \
                       __builtin_amdgcn_rcpf(C2 * D2), a[j][1]); \
    }

    LOADS(A, 0, 0)
#pragma unroll 4
    for (int s = 0; s < 32; s += 2) {
        LOADS(B, 512, s + 1)          // prefetch s+1 while computing s
        COMP(A)
        ekg += 1024;
        LOADS(A, 0, s + 2)            // prefetch s+2 (over-read guarded by ws)
        COMP(B)
    }
#undef LOADS
#undef COMP

    // combine the 8 uc partials per (q, k): packed contiguous float4 writes
    {
        float4 p0 = {a[0][0], a[0][1], a[1][0], a[1][1]};
        float4 p1 = {a[2][0], a[2][1], a[3][0], a[3][1]};
        *(float4*)&red[uc][kp][0] = p0;
        *(float4*)&red[uc][kp][4] = p1;
    }
    __syncthreads();
    {
        int j = tid >> 7, k = tid & 127;
        int kp2 = k >> 1, idx = j * 2 + (k & 1);
        float s = 0.f;
#pragma unroll
        for (int u = 0; u < 8; u++) s += red[u][kp2][idx];
        sc[j][k] = vsum - 2.f * s;
    }
    __syncthreads();

    // softmax over k (128): waves 0..3 handle q-row j=w; lanes cover k, k+64
    int w = tid >> 6, lane = tid & 63;
    if (w < 4) {
        int j = w;
        float s1 = sc[j][lane], s2 = sc[j][lane + 64];
        float m = wave_max(fmaxf(s1, s2));
        float e1 = __builtin_amdgcn_exp2f((s1 - m) * L2E);
        float e2 = __builtin_amdgcn_exp2f((s2 - m) * L2E);
        float ssum = wave_sum(e1 + e2);
        float inv = __builtin_amdgcn_rcpf(ssum);
        float p1 = e1 * inv, p2 = e2 * inv;
        sct[lane][j] = p1; sct[lane + 64][j] = p2;
        float* o = out_sc + ((q0 + j) * 32 + b) * 128;
        o[lane] = p1; o[lane + 64] = p2;
    }
    __syncthreads();

    // context[j][n] = sum_k p[j][k] * keys[k][b][n]; thread owns 2 n, 4 rows
    {
        int n0 = tid * 2;
        const float* kbase = keys + b * 1024 + n0;
        float2 c0{0.f, 0.f}, c1{0.f, 0.f}, c2{0.f, 0.f}, c3{0.f, 0.f};
#pragma unroll 4
        for (int k = 0; k < 128; k++) {
            float2 kv = *(const float2*)(kbase + k * 32768);
            float4 p4 = *(const float4*)&sct[k][0];
            c0.x = fmaf(p4.x, kv.x, c0.x); c0.y = fmaf(p4.x, kv.y, c0.y);
            c1.x = fmaf(p4.y, kv.x, c1.x); c1.y = fmaf(p4.y, kv.y, c1.y);
            c2.x = fmaf(p4.z, kv.x, c2.x); c2.y = fmaf(p4.z, kv.y, c2.y);
            c3.x = fmaf(p4.w, kv.x, c3.x); c3.y = fmaf(p4.w, kv.y, c3.y);
        }
        *(float2*)(out_ctx + ((q0 + 0) * 32 + b) * 1024 + n0) = c0;
        *(float2*)(out_ctx + ((q0 + 1) * 32 + b) * 1024 + n0) = c1;
        *(float2*)(out_ctx + ((q0 + 2) * 32 + b) * 1024 + n0) = c2;
        *(float2*)(out_ctx + ((q0 + 3) * 32 + b) * 1024 + n0) = c3;
    }
}

extern "C" void kernel_launch(void* const* d_in, const int* in_sizes, int n_in,
                              void* d_out, int out_size, void* d_ws, size_t ws_size,
                              hipStream_t stream) {
    const float* query = (const float*)d_in[0];
    const float* keys  = (const float*)d_in[1];
    const float* Wq    = (const float*)d_in[2];
    const float* Wk    = (const float*)d_in[3];
    const float* la    = (const float*)d_in[4];
    const float* ns    = (const float*)d_in[5];
    const float* bias  = (const float*)d_in[6];

    float* out_ctx = (float*)d_out;             // 64*32*1024
    float* out_sc  = (float*)d_out + 2097152;   // 64*32*128

    char* ws = (char*)d_ws;                     // ~38 MB used
    float* v   = (float*)(ws);                  // 1025 floats
    float* ej  = (float*)(ws + 8192);           // 8 MB  [2048 rows][1024 u]
    float* ek2 = (float*)(ws + 8192 + 8388608); // 16 MB [b][u][k]
    unsigned short* qb  = (unsigned short*)(ws + 8192 + 8388608 + 16777216);
    unsigned short* kb  = qb + 2097152;
    unsigned short* wqb = kb + 4194304;
    unsigned short* wkb = wqb + 1048576;

    convert_kernel<<<8193, 256, 0, stream>>>(query, keys, Wq, Wk, qb, kb, wqb, wkb,
                                             la, ns, v);
    proj_gemm<<<dim3(8, 96), 256, 0, stream>>>(qb, kb, wqb, wkb, bias, ej, ek2);
    score_all<<<dim3(32, 16), 512, 0, stream>>>(ej, ek2, v, keys, out_ctx, out_sc);
}